// Round 1
// baseline (637.269 us; speedup 1.0000x reference)
//
#include <hip/hip_runtime.h>
#include <math.h>

#define Bq 32
#define Cq 256
#define Hq 96
#define Wq 96
#define HWq (Hq * Wq)      // 9216
#define KKq 9
#define CKq (Cq * KKq)     // 2304

// ---------------- Kernel 1: global average pool per (b,c) plane ----------------
__global__ __launch_bounds__(256) void pool_kernel(const float* __restrict__ x,
                                                   float* __restrict__ pooled) {
    int plane = blockIdx.x;  // b*C + c
    const float4* px = (const float4*)(x + (size_t)plane * HWq);
    int t = threadIdx.x;
    float s = 0.f;
#pragma unroll
    for (int i = 0; i < 9; ++i) {       // 2304 float4 / 256 threads
        float4 v = px[t + i * 256];
        s += v.x + v.y + v.z + v.w;
    }
    // wave64 reduce
    for (int off = 32; off > 0; off >>= 1) s += __shfl_down(s, off, 64);
    __shared__ float wsum[4];
    if ((t & 63) == 0) wsum[t >> 6] = s;
    __syncthreads();
    if (t == 0) {
        pooled[plane] = (wsum[0] + wsum[1] + wsum[2] + wsum[3]) * (1.0f / HWq);
    }
}

// ---------------- Kernel 2: h = gelu(pooled @ w1.T + b1), exact GELU ----------------
__global__ __launch_bounds__(256) void fc1_kernel(const float* __restrict__ pooled,
                                                  const float* __restrict__ w1,
                                                  const float* __restrict__ b1,
                                                  float* __restrict__ h) {
    int b = blockIdx.x;
    int j = threadIdx.x;
    __shared__ float p[Cq];
    p[j] = pooled[b * Cq + j];
    __syncthreads();
    const float4* wrow = (const float4*)(w1 + (size_t)j * Cq);  // w1[j][k], contiguous
    float acc = b1[j];
#pragma unroll 4
    for (int k = 0; k < Cq / 4; ++k) {
        float4 w = wrow[k];
        acc += p[4 * k] * w.x + p[4 * k + 1] * w.y + p[4 * k + 2] * w.z + p[4 * k + 3] * w.w;
    }
    float g = 0.5f * acc * (1.0f + erff(acc * 0.70710678118654752440f));
    h[b * Cq + j] = g;
}

// ---------------- Kernel 3: wdyn = h @ w2.T + b2  → (B, C*9) ----------------
__global__ __launch_bounds__(256) void fc2_kernel(const float* __restrict__ hbuf,
                                                  const float* __restrict__ w2,
                                                  const float* __restrict__ b2,
                                                  float* __restrict__ wdyn) {
    int b = blockIdx.y;
    int m = blockIdx.x * 256 + threadIdx.x;  // 0..2303
    __shared__ float hs[Cq];
    hs[threadIdx.x] = hbuf[b * Cq + threadIdx.x];
    __syncthreads();
    const float4* wrow = (const float4*)(w2 + (size_t)m * Cq);  // w2[m][k], contiguous
    float acc = b2[m];
#pragma unroll 4
    for (int k = 0; k < Cq / 4; ++k) {
        float4 w = wrow[k];
        acc += hs[4 * k] * w.x + hs[4 * k + 1] * w.y + hs[4 * k + 2] * w.z + hs[4 * k + 3] * w.w;
    }
    wdyn[b * CKq + m] = acc;
}

// ---------------- Kernel 4: reflect-pad 3x3 conv with per-plane dynamic weights ----------------
// out[h][w] = sum_{i,j} wd[i*3+j] * x[reflect(h+i-1)][reflect(w+j-1)]
__global__ __launch_bounds__(256) void conv_kernel(const float* __restrict__ x,
                                                   const float* __restrict__ wdyn,
                                                   float* __restrict__ out) {
    int plane = blockIdx.x;  // b*C + c
    const float* xp = x + (size_t)plane * HWq;
    float* op = out + (size_t)plane * HWq;
    const float* wd = wdyn + (size_t)plane * KKq;
    // broadcast load of the 9 weights (same address across lanes)
    float w0 = wd[0], w1 = wd[1], w2 = wd[2];
    float w3 = wd[3], w4 = wd[4], w5 = wd[5];
    float w6 = wd[6], w7 = wd[7], w8 = wd[8];
    int t = threadIdx.x;
#pragma unroll
    for (int it = 0; it < 9; ++it) {
        int g = t + it * 256;        // group of 4 outputs; 2304 groups per plane
        int hh = g / 24;             // output row
        int wq = (g % 24) * 4;       // output col of first element (aligned)
        int rm = (hh == 0) ? 1 : hh - 1;    // reflect: -1 -> 1
        int rp = (hh == 95) ? 94 : hh + 1;  // reflect: 96 -> 94
        const float* r0 = xp + rm * Wq;
        const float* r1 = xp + hh * Wq;
        const float* r2 = xp + rp * Wq;
        int li = (wq == 0) ? 1 : wq - 1;    // reflect left
        int ri = (wq == 92) ? 94 : wq + 4;  // reflect right (wq+4 == 96)
        float4 c0 = *(const float4*)(r0 + wq);
        float4 c1 = *(const float4*)(r1 + wq);
        float4 c2 = *(const float4*)(r2 + wq);
        float l0 = r0[li], l1 = r1[li], l2 = r2[li];
        float q0 = r0[ri], q1 = r1[ri], q2 = r2[ri];
        float4 o;
        // row above (taps w0,w1,w2): v = {l0, c0.x, c0.y, c0.z, c0.w, q0}
        o.x = w0 * l0    + w1 * c0.x + w2 * c0.y;
        o.y = w0 * c0.x  + w1 * c0.y + w2 * c0.z;
        o.z = w0 * c0.y  + w1 * c0.z + w2 * c0.w;
        o.w = w0 * c0.z  + w1 * c0.w + w2 * q0;
        // same row (taps w3,w4,w5)
        o.x += w3 * l1   + w4 * c1.x + w5 * c1.y;
        o.y += w3 * c1.x + w4 * c1.y + w5 * c1.z;
        o.z += w3 * c1.y + w4 * c1.z + w5 * c1.w;
        o.w += w3 * c1.z + w4 * c1.w + w5 * q1;
        // row below (taps w6,w7,w8)
        o.x += w6 * l2   + w7 * c2.x + w8 * c2.y;
        o.y += w6 * c2.x + w7 * c2.y + w8 * c2.z;
        o.z += w6 * c2.y + w7 * c2.z + w8 * c2.w;
        o.w += w6 * c2.z + w7 * c2.w + w8 * q2;
        *(float4*)(op + (size_t)g * 4) = o;   // g*4 == hh*96 + wq
    }
}

extern "C" void kernel_launch(void* const* d_in, const int* in_sizes, int n_in,
                              void* d_out, int out_size, void* d_ws, size_t ws_size,
                              hipStream_t stream) {
    const float* x  = (const float*)d_in[0];
    const float* w1 = (const float*)d_in[1];
    const float* b1 = (const float*)d_in[2];
    const float* w2 = (const float*)d_in[3];
    const float* b2 = (const float*)d_in[4];
    float* out = (float*)d_out;

    float* pooled = (float*)d_ws;            // 8192 floats
    float* h      = pooled + Bq * Cq;        // 8192 floats
    float* wdyn   = h + Bq * Cq;             // 73728 floats

    pool_kernel<<<Bq * Cq, 256, 0, stream>>>(x, pooled);
    fc1_kernel<<<Bq, 256, 0, stream>>>(pooled, w1, b1, h);
    fc2_kernel<<<dim3(CKq / 256, Bq), 256, 0, stream>>>(h, w2, b2, wdyn);
    conv_kernel<<<Bq * Cq, 256, 0, stream>>>(x, wdyn, out);
}

// Round 2
// 634.277 us; speedup vs baseline: 1.0047x; 1.0047x over previous
//
#include <hip/hip_runtime.h>
#include <math.h>

#define Bq 32
#define Cq 256
#define Hq 96
#define Wq 96
#define HWq (Hq * Wq)      // 9216
#define KKq 9
#define CKq (Cq * KKq)     // 2304
#define NPLANES (Bq * Cq)  // 8192

// ---------------- Kernel 1: global average pool per (b,c) plane ----------------
__global__ __launch_bounds__(256) void pool_kernel(const float* __restrict__ x,
                                                   float* __restrict__ pooled) {
    int plane = blockIdx.x;  // b*C + c
    const float4* px = (const float4*)(x + (size_t)plane * HWq);
    int t = threadIdx.x;
    float s = 0.f;
#pragma unroll
    for (int i = 0; i < 9; ++i) {       // 2304 float4 / 256 threads
        float4 v = px[t + i * 256];
        s += v.x + v.y + v.z + v.w;
    }
    // wave64 reduce
    for (int off = 32; off > 0; off >>= 1) s += __shfl_down(s, off, 64);
    __shared__ float wsum[4];
    if ((t & 63) == 0) wsum[t >> 6] = s;
    __syncthreads();
    if (t == 0) {
        pooled[plane] = (wsum[0] + wsum[1] + wsum[2] + wsum[3]) * (1.0f / HWq);
    }
}

// ---------------- Kernel 2: h = gelu(pooled @ w1.T + b1), exact GELU ----------------
__global__ __launch_bounds__(256) void fc1_kernel(const float* __restrict__ pooled,
                                                  const float* __restrict__ w1,
                                                  const float* __restrict__ b1,
                                                  float* __restrict__ h) {
    int b = blockIdx.x;
    int j = threadIdx.x;
    __shared__ float p[Cq];
    p[j] = pooled[b * Cq + j];
    __syncthreads();
    const float4* wrow = (const float4*)(w1 + (size_t)j * Cq);  // w1[j][k], contiguous
    float acc = b1[j];
#pragma unroll 4
    for (int k = 0; k < Cq / 4; ++k) {
        float4 w = wrow[k];
        acc += p[4 * k] * w.x + p[4 * k + 1] * w.y + p[4 * k + 2] * w.z + p[4 * k + 3] * w.w;
    }
    float g = 0.5f * acc * (1.0f + erff(acc * 0.70710678118654752440f));
    h[b * Cq + j] = g;
}

// ---------------- Kernel 3: wdyn = h @ w2.T + b2  → (B, C*9) ----------------
__global__ __launch_bounds__(256) void fc2_kernel(const float* __restrict__ hbuf,
                                                  const float* __restrict__ w2,
                                                  const float* __restrict__ b2,
                                                  float* __restrict__ wdyn) {
    int b = blockIdx.y;
    int m = blockIdx.x * 256 + threadIdx.x;  // 0..2303
    __shared__ float hs[Cq];
    hs[threadIdx.x] = hbuf[b * Cq + threadIdx.x];
    __syncthreads();
    const float4* wrow = (const float4*)(w2 + (size_t)m * Cq);  // w2[m][k], contiguous
    float acc = b2[m];
#pragma unroll 4
    for (int k = 0; k < Cq / 4; ++k) {
        float4 w = wrow[k];
        acc += hs[4 * k] * w.x + hs[4 * k + 1] * w.y + hs[4 * k + 2] * w.z + hs[4 * k + 3] * w.w;
    }
    wdyn[b * CKq + m] = acc;
}

// ---------------- Kernel 4: reflect-pad 3x3 conv with per-plane dynamic weights ----------------
// out[h][w] = sum_{i,j} wd[i*3+j] * x[reflect(h+i-1)][reflect(w+j-1)]
// grid = (NPLANES, 3); each block does 3 groups/thread (768 groups of the
// plane's 2304). Plane index REVERSED so conv's first reads hit the tail of x
// that pool_kernel just left resident in the 256 MB L3.
__global__ __launch_bounds__(256) void conv_kernel(const float* __restrict__ x,
                                                   const float* __restrict__ wdyn,
                                                   float* __restrict__ out) {
    int plane = (NPLANES - 1) - blockIdx.x;
    const float* xp = x + (size_t)plane * HWq;
    float* op = out + (size_t)plane * HWq;
    const float* wd = wdyn + (size_t)plane * KKq;
    // broadcast load of the 9 weights (same address across lanes)
    float w0 = wd[0], w1 = wd[1], w2 = wd[2];
    float w3 = wd[3], w4 = wd[4], w5 = wd[5];
    float w6 = wd[6], w7 = wd[7], w8 = wd[8];
    int t = threadIdx.x;
    int gbase = t + blockIdx.y * 768;
#pragma unroll
    for (int it = 0; it < 3; ++it) {
        int g = gbase + it * 256;    // group of 4 outputs; 2304 groups per plane
        int hh = g / 24;             // output row
        int wq = (g % 24) * 4;       // output col of first element (aligned)
        int rm = (hh == 0) ? 1 : hh - 1;    // reflect: -1 -> 1
        int rp = (hh == 95) ? 94 : hh + 1;  // reflect: 96 -> 94
        const float* r0 = xp + rm * Wq;
        const float* r1 = xp + hh * Wq;
        const float* r2 = xp + rp * Wq;
        int li = (wq == 0) ? 1 : wq - 1;    // reflect left
        int ri = (wq == 92) ? 94 : wq + 4;  // reflect right (wq+4 == 96)
        float4 c0 = *(const float4*)(r0 + wq);
        float4 c1 = *(const float4*)(r1 + wq);
        float4 c2 = *(const float4*)(r2 + wq);
        float l0 = r0[li], l1 = r1[li], l2 = r2[li];
        float q0 = r0[ri], q1 = r1[ri], q2 = r2[ri];
        float4 o;
        // row above (taps w0,w1,w2)
        o.x = w0 * l0    + w1 * c0.x + w2 * c0.y;
        o.y = w0 * c0.x  + w1 * c0.y + w2 * c0.z;
        o.z = w0 * c0.y  + w1 * c0.z + w2 * c0.w;
        o.w = w0 * c0.z  + w1 * c0.w + w2 * q0;
        // same row (taps w3,w4,w5)
        o.x += w3 * l1   + w4 * c1.x + w5 * c1.y;
        o.y += w3 * c1.x + w4 * c1.y + w5 * c1.z;
        o.z += w3 * c1.y + w4 * c1.z + w5 * c1.w;
        o.w += w3 * c1.z + w4 * c1.w + w5 * q1;
        // row below (taps w6,w7,w8)
        o.x += w6 * l2   + w7 * c2.x + w8 * c2.y;
        o.y += w6 * c2.x + w7 * c2.y + w8 * c2.z;
        o.z += w6 * c2.y + w7 * c2.z + w8 * c2.w;
        o.w += w6 * c2.z + w7 * c2.w + w8 * q2;
        *(float4*)(op + (size_t)g * 4) = o;   // g*4 == hh*96 + wq
    }
}

extern "C" void kernel_launch(void* const* d_in, const int* in_sizes, int n_in,
                              void* d_out, int out_size, void* d_ws, size_t ws_size,
                              hipStream_t stream) {
    const float* x  = (const float*)d_in[0];
    const float* w1 = (const float*)d_in[1];
    const float* b1 = (const float*)d_in[2];
    const float* w2 = (const float*)d_in[3];
    const float* b2 = (const float*)d_in[4];
    float* out = (float*)d_out;

    float* pooled = (float*)d_ws;            // 8192 floats
    float* h      = pooled + Bq * Cq;        // 8192 floats
    float* wdyn   = h + Bq * Cq;             // 73728 floats

    pool_kernel<<<NPLANES, 256, 0, stream>>>(x, pooled);
    fc1_kernel<<<Bq, 256, 0, stream>>>(pooled, w1, b1, h);
    fc2_kernel<<<dim3(CKq / 256, Bq), 256, 0, stream>>>(h, w2, b2, wdyn);
    conv_kernel<<<dim3(NPLANES, 3), 256, 0, stream>>>(x, wdyn, out);
}